// Round 14
// baseline (166.751 us; speedup 1.0000x reference)
//
#include <hip/hip_runtime.h>

#define NN 10000
#define NCAND 201
#define NB 64

typedef __attribute__((ext_vector_type(8))) short short8;
typedef __attribute__((ext_vector_type(4))) float f32x4;

__device__ __forceinline__ float bf2f(unsigned short u) {
  return __uint_as_float(((unsigned int)u) << 16);
}
__device__ __forceinline__ unsigned short f2bf(float f) {
  unsigned int u = __float_as_uint(f);
  u += 0x7FFFu + ((u >> 16) & 1u);   // RNE
  return (unsigned short)(u >> 16);
}
__device__ __forceinline__ float fast_tanh(float x) {
  return 1.0f - 2.0f / (__expf(2.0f * x) + 1.0f);
}
// generic load: flag=1 -> float32 array, flag=0 -> bf16 array
__device__ __forceinline__ float gld(const void* p, long i, int f) {
  return f ? ((const float*)p)[i] : bf2f(((const unsigned short*)p)[i]);
}

// ---------------------------------------------------------------------------
// MEGA launch (everything with no intra-launch dependencies):
//  [0,1024)    : feat_pool role -- atomic-free partial pooling into
//                psumP/pmaxP[(b*16+s)*128+col] (no zero-init dependency).
//  [1024,1472) : actorA role -- candidate h1 -> layer2 features cf -> cfw.
//  [1472,1856) : transpose aw1t/aw2t/cw1t/cw2t (256-sample self-detect).
//  [1856,1873) : F[j] per-array f32 flags.  1873: mask mode.  1874: cand
//                width + zero scnt.
// ---------------------------------------------------------------------------
__global__ __launch_bounds__(256, 4)
void mega_kernel(const void* __restrict__ x, const int* __restrict__ cand,
                 const void* w1, const void* b1, const void* w2, const void* b2,
                 const void* aw1, const void* ab1, const void* aw2, const void* ab2,
                 const void* aw3, const void* ab3,
                 const void* cw1, const void* cb1, const void* cw2, const void* cb2,
                 const void* cw3, const void* cb3,
                 const unsigned int* mask_w, const unsigned int* cand_w,
                 int* F, int* scnt,
                 float* __restrict__ psumP, float* __restrict__ pmaxP,
                 unsigned short* __restrict__ cfw,
                 unsigned short* __restrict__ aw1t, unsigned short* __restrict__ aw2t,
                 unsigned short* __restrict__ cw1t, unsigned short* __restrict__ cw2t) {
  __shared__ __align__(16) unsigned short pool[128 * 72];  // 18432 B overlay
  __shared__ float w1f[3 * 64];
  __shared__ float b1f[64];
  __shared__ float b2f[128];
  __shared__ int cnts[8];

  const int t = threadIdx.x;
  const int j = blockIdx.x;
  const int lane = t & 63;
  const int wv = t >> 6;

  if (j < 1472) {
    // ---- shared self-detect for fp/actorA roles: x,w1,b1,b2,w2,cand ----
    if (t < 8) cnts[t] = 0;
    __syncthreads();
    {
      if ((((const unsigned short*)x)[t] & 0x7F80u) >= 0x4300u) atomicAdd(&cnts[0], 1);
      if (t < 192 && (((const unsigned short*)w1)[t] & 0x7F80u) >= 0x4300u) atomicAdd(&cnts[1], 1);
      if (t < 64 && (((const unsigned short*)b1)[t] & 0x7F80u) >= 0x4300u) atomicAdd(&cnts[2], 1);
      if (t < 128 && (((const unsigned short*)b2)[t] & 0x7F80u) >= 0x4300u) atomicAdd(&cnts[3], 1);
      if ((((const unsigned short*)w2)[t] & 0x7F80u) >= 0x4300u) atomicAdd(&cnts[4], 1);
      int co = 0;
#pragma unroll
      for (int q = 0; q < 4; ++q) {
        int i = t * 4 + q;
        if ((i & 1) && cand_w[i] != 0u) co = 1;
      }
      if (co) atomicAdd(&cnts[5], 1);
    }
    __syncthreads();
    const int F0 = cnts[0] > 32, F1 = cnts[1] > 24, F2 = cnts[2] > 8;
    const int F4 = cnts[3] > 16, Fw2 = cnts[4] > 32, C64 = cnts[5] == 0;

    if (j < 1024) {
      // ================= feat_pool role =================
      unsigned short* h1s = pool;  // [128][72]
      const int b = j >> 4;
      const int s = j & 15;

      if (t < 192) w1f[t] = gld(w1, t, F1);
      if (t < 64) b1f[t] = gld(b1, t, F2);
      if (t < 128) b2f[t] = gld(b2, t, F4);

      // B fragments gathered from fe_w2 [k][n] (strided scalar, once/block)
      short8 bfr[2][2];
#pragma unroll
      for (int nl = 0; nl < 2; ++nl)
#pragma unroll
        for (int ks = 0; ks < 2; ++ks) {
          int col = wv * 32 + nl * 16 + (lane & 15);
          short8 v;
#pragma unroll
          for (int jj = 0; jj < 8; ++jj) {
            int k = (lane >> 4) * 8 + ks * 32 + jj;
            v[jj] = (short)f2bf(gld(w2, (long)k * 128 + col, Fw2));
          }
          bfr[nl][ks] = v;
        }
      __syncthreads();

      float csum[2] = {0.f, 0.f};
      float cmax[2] = {0.f, 0.f};
      const int m = t & 127;
      const int kg = t >> 7;

      float x0 = 0.f, x1 = 0.f, x2 = 0.f;
      if (s < 79) {
        int nb = s * 128;
        if (m < min(128, NN - nb)) {
          long xo = ((long)b * NN + nb + m) * 3;
          x0 = gld(x, xo, F0); x1 = gld(x, xo + 1, F0); x2 = gld(x, xo + 2, F0);
        }
      }

      for (int c = s; c < 79; c += 16) {
        int nb = c * 128;
        int cnt = (nb + 128 <= NN) ? 128 : (NN - nb);
        if (m < cnt) {
#pragma unroll
          for (int blk = 0; blk < 4; ++blk) {
            short8 v;
#pragma unroll
            for (int i = 0; i < 8; ++i) {
              int k = kg * 32 + blk * 8 + i;
              float vv = x0 * w1f[k] + x1 * w1f[64 + k] + x2 * w1f[128 + k] + b1f[k];
              v[i] = (short)f2bf(fmaxf(vv, 0.f));
            }
            *(short8*)(h1s + m * 72 + kg * 32 + blk * 8) = v;
          }
        }
        {
          int cn = c + 16;
          float nx0 = 0.f, nx1 = 0.f, nx2 = 0.f;
          if (cn < 79) {
            int nbn = cn * 128;
            if (m < min(128, NN - nbn)) {
              long xo = ((long)b * NN + nbn + m) * 3;
              nx0 = gld(x, xo, F0); nx1 = gld(x, xo + 1, F0); nx2 = gld(x, xo + 2, F0);
            }
          }
          __syncthreads();
          x0 = nx0; x1 = nx1; x2 = nx2;
        }
#pragma unroll
        for (int mt = 0; mt < 8; ++mt) {
          const unsigned short* ap = h1s + (mt * 16 + (lane & 15)) * 72 + ((lane >> 4) * 8);
          short8 af0 = *(const short8*)(ap);
          short8 af1 = *(const short8*)(ap + 32);
#pragma unroll
          for (int nl = 0; nl < 2; ++nl) {
            f32x4 acc = {0.f, 0.f, 0.f, 0.f};
            acc = __builtin_amdgcn_mfma_f32_16x16x32_bf16(af0, bfr[nl][0], acc, 0, 0, 0);
            acc = __builtin_amdgcn_mfma_f32_16x16x32_bf16(af1, bfr[nl][1], acc, 0, 0, 0);
            int col = wv * 32 + nl * 16 + (lane & 15);
            float bb = b2f[col];
#pragma unroll
            for (int r = 0; r < 4; ++r) {
              int row = mt * 16 + ((lane >> 4) * 4) + r;
              if (row < cnt) {
                float v = fmaxf(acc[r] + bb, 0.f);
                csum[nl] += v;
                cmax[nl] = fmaxf(cmax[nl], v);
              }
            }
          }
        }
        __syncthreads();
      }
#pragma unroll
      for (int nl = 0; nl < 2; ++nl) {
        csum[nl] += __shfl_xor(csum[nl], 16);
        csum[nl] += __shfl_xor(csum[nl], 32);
        cmax[nl] = fmaxf(cmax[nl], __shfl_xor(cmax[nl], 16));
        cmax[nl] = fmaxf(cmax[nl], __shfl_xor(cmax[nl], 32));
      }
      if (lane < 16) {
#pragma unroll
        for (int nl = 0; nl < 2; ++nl) {
          int col = wv * 32 + nl * 16 + lane;
          psumP[((long)b * 16 + s) * 128 + col] = csum[nl];   // plain stores
          pmaxP[((long)b * 16 + s) * 128 + col] = cmax[nl];
        }
      }
    } else {
      // ================= actorA role: h1c -> cf -> cfw =================
      unsigned short* h1c = pool;           // [32][72]
      const int idx = j - 1024;
      const int b = idx / 7;
      const int cb = idx % 7;
      const int cbase = cb * 29;

      if (t < 128) b2f[t] = gld(b2, t, F4);

      {
        int r = t & 31;
        int ci = cbase + r;
        if (ci > NCAND - 1) ci = NCAND - 1;
        long cidx = (long)b * NCAND + ci;
        int nd = C64 ? cand[2 * cidx] : cand[cidx];
        long xo = ((long)b * NN + nd) * 3;
        float x0 = gld(x, xo, F0), x1 = gld(x, xo + 1, F0), x2 = gld(x, xo + 2, F0);
        int kg = t >> 5;
#pragma unroll
        for (int i = 0; i < 8; ++i) {
          int k = kg * 8 + i;
          float v = x0 * gld(w1, k, F1) + x1 * gld(w1, 64 + k, F1) +
                    x2 * gld(w1, 128 + k, F1) + gld(b1, k, F2);
          h1c[r * 72 + k] = f2bf(fmaxf(v, 0.f));
        }
      }
      __syncthreads();

      {
        short8 af[2][2];
#pragma unroll
        for (int mt = 0; mt < 2; ++mt)
#pragma unroll
          for (int ks = 0; ks < 2; ++ks)
            af[mt][ks] = *(const short8*)(h1c + (mt * 16 + (lane & 15)) * 72 + ((lane >> 4) * 8) + ks * 32);
#pragma unroll
        for (int nl = 0; nl < 2; ++nl) {
          int col = wv * 32 + nl * 16 + (lane & 15);
          short8 bf0, bf1;
#pragma unroll
          for (int jj = 0; jj < 8; ++jj) {
            int k = (lane >> 4) * 8 + jj;
            bf0[jj] = (short)f2bf(gld(w2, (long)k * 128 + col, Fw2));
            bf1[jj] = (short)f2bf(gld(w2, (long)(k + 32) * 128 + col, Fw2));
          }
          float bb = b2f[col];
#pragma unroll
          for (int mt = 0; mt < 2; ++mt) {
            f32x4 acc = {0.f, 0.f, 0.f, 0.f};
            acc = __builtin_amdgcn_mfma_f32_16x16x32_bf16(af[mt][0], bf0, acc, 0, 0, 0);
            acc = __builtin_amdgcn_mfma_f32_16x16x32_bf16(af[mt][1], bf1, acc, 0, 0, 0);
#pragma unroll
            for (int r = 0; r < 4; ++r) {
              int row = mt * 16 + ((lane >> 4) * 4) + r;
              cfw[(long)idx * 4096 + row * 128 + col] = f2bf(fmaxf(acc[r] + bb, 0.f));
            }
          }
        }
      }
    }
    return;
  }

  // ---- housekeeping roles ----
  if (t < 8) cnts[t] = 0;
  __syncthreads();

  if (j < 1856) {
    const unsigned short* pa = (const unsigned short*)aw1;
    const unsigned short* pb = (const unsigned short*)aw2;
    const unsigned short* pc = (const unsigned short*)cw1;
    const unsigned short* pd = (const unsigned short*)cw2;
    if ((pa[t] & 0x7F80u) >= 0x4300u) atomicAdd(&cnts[0], 1);
    if ((pb[t] & 0x7F80u) >= 0x4300u) atomicAdd(&cnts[1], 1);
    if ((pc[t] & 0x7F80u) >= 0x4300u) atomicAdd(&cnts[2], 1);
    if ((pd[t] & 0x7F80u) >= 0x4300u) atomicAdd(&cnts[3], 1);
    __syncthreads();
    const int Faw1 = cnts[0] > 32, Faw2 = cnts[1] > 32;
    const int Fcw1 = cnts[2] > 32, Fcw2 = cnts[3] > 32;
    int i = (j - 1472) * 256 + t;
    if (i < 256 * 384) { int n = i / 384, k = i % 384; aw1t[i] = f2bf(gld(aw1, k * 256 + n, Faw1)); }
    if (i < 256 * 256) {
      int n = i >> 8, k = i & 255;
      aw2t[i] = f2bf(gld(aw2, k * 256 + n, Faw2));
      cw1t[i] = f2bf(gld(cw1, k * 256 + n, Fcw1));
      cw2t[i] = f2bf(gld(cw2, k * 256 + n, Fcw2));
    }
  } else if (j < 1873) {
    const void* ptrs[17] = {x, w1, b1, w2, b2, aw1, ab1, aw2, ab2, aw3, ab3,
                            cw1, cb1, cw2, cb2, cw3, cb3};
    const int sizes[17] = {1920000, 192, 64, 8192, 128, 98304, 256, 65536, 256,
                           256, 1, 65536, 256, 65536, 256, 256, 1};
    int a = j - 1856;
    const unsigned short* p = (const unsigned short*)ptrs[a];
    int K = min(sizes[a], 2048);
    int c = 0;
    for (int i = t; i < K; i += 256)
      if ((p[i] & 0x7F80u) >= 0x4300u) c++;
    if (c) atomicAdd(&cnts[0], c);
    __syncthreads();
    if (t == 0) F[a] = (cnts[0] > (K >> 3)) ? 1 : 0;
  } else if (j == 1873) {
    int flo = 0, fhi = 0, fgt = 0;
    for (int i = t; i < 3216; i += 256) {
      unsigned int w = mask_w[i];
      if ((w & 0xFFFFu) == 0x3F80u) flo = 1;
      if ((w >> 16) == 0x3F80u) fhi = 1;
      if (w > 1u) fgt = 1;
    }
    if (flo) cnts[0] = 1;
    if (fhi) cnts[1] = 1;
    if (fgt) cnts[2] = 1;
    __syncthreads();
    if (t == 0) F[17] = cnts[0] ? 2 : (cnts[1] ? 3 : (cnts[2] ? 1 : 0));
  } else {
    int co = 0;
    for (int i = t; i < 1024; i += 256)
      if ((i & 1) && cand_w[i] != 0u) co = 1;
    if (co) cnts[0] = 1;
    if (t < 64) scnt[t] = 0;
    __syncthreads();
    if (t == 0) F[18] = cnts[0] ? 0 : 1;
  }
}

// ---------------------------------------------------------------------------
// actorBC: blocks 0..447 = actor layers 1-3 (pact computed LOCALLY per block
// -- bit-identical replication of the old pp role, removes one launch);
// blocks 448..511 = critic. Last actor block per batch runs masked softmax
// (scnt counters; scores via device-scope atomicExch / atomicAdd(p,0) reads).
// ---------------------------------------------------------------------------
__global__ __launch_bounds__(256)
void actorBC_kernel(const unsigned short* __restrict__ cfw,
                    const void* __restrict__ ab1, const void* __restrict__ ab2,
                    const void* __restrict__ aw3, const void* __restrict__ ab3,
                    const void* __restrict__ mask,
                    const int* __restrict__ F,
                    const float* __restrict__ psumP, const float* __restrict__ pmaxP,
                    const unsigned short* __restrict__ aw1t,
                    const unsigned short* __restrict__ aw2t,
                    const unsigned short* __restrict__ cw1t,
                    const unsigned short* __restrict__ cw2t,
                    const void* __restrict__ cb1, const void* __restrict__ cb2,
                    const void* __restrict__ cw3, const void* __restrict__ cb3,
                    float* __restrict__ scores, int* __restrict__ scnt,
                    void* __restrict__ out) {
  __shared__ __align__(16) unsigned short a1s[32 * 264];
  __shared__ __align__(16) unsigned short a2s[32 * 264];
  __shared__ float plf[256];
  __shared__ float pactS[256];
  __shared__ float red[4];
  __shared__ int amLast;

  const int t = threadIdx.x;
  const int lane = t & 63;
  const int wv = t >> 6;

  if (blockIdx.x >= 448) {
    // ================= critic role =================
    const int b = blockIdx.x - 448;
    float* c1f = pactS;  // reuse
    const int OF = (F[0] + F[1] + F[3] + F[5] + F[7] + F[9] + F[11] + F[13] + F[15]) >= 5;
    const int F12 = F[12], F14 = F[14], F15 = F[15], F16 = F[16];
    float ssum = 0.f, smax = 0.f;
    if (t < 128) {
#pragma unroll
      for (int sl = 0; sl < 16; ++sl) {
        ssum += psumP[((long)b * 16 + sl) * 128 + t];
        smax = fmaxf(smax, pmaxP[((long)b * 16 + sl) * 128 + t]);
      }
      plf[t] = ssum * (1.0f / 10000.0f);
      plf[128 + t] = smax;
    }
    __syncthreads();
    {
      float a = gld(cb1, t, F12);
      const unsigned short* row = cw1t + t * 256;
#pragma unroll
      for (int k8 = 0; k8 < 32; ++k8) {
        short8 w = *(const short8*)(row + k8 * 8);
#pragma unroll
        for (int j = 0; j < 8; ++j)
          a += plf[k8 * 8 + j] * bf2f((unsigned short)w[j]);
      }
      c1f[t] = fast_tanh(a);
    }
    __syncthreads();
    {
      float a2 = gld(cb2, t, F14);
      const unsigned short* row = cw2t + t * 256;
#pragma unroll
      for (int k8 = 0; k8 < 32; ++k8) {
        short8 w = *(const short8*)(row + k8 * 8);
#pragma unroll
        for (int j = 0; j < 8; ++j)
          a2 += c1f[k8 * 8 + j] * bf2f((unsigned short)w[j]);
      }
      a2 = fast_tanh(a2);
      float p = a2 * gld(cw3, t, F15);
      for (int o = 32; o; o >>= 1) p += __shfl_xor(p, o);
      __syncthreads();
      if (lane == 0) red[wv] = p;
      __syncthreads();
      if (t == 0) {
        float v = red[0] + red[1] + red[2] + red[3] + gld(cb3, 0, F16);
        if (!(v == v)) v = 0.f;  // scrub
        if (OF) ((float*)out)[NB * NCAND + b] = v;
        else ((unsigned short*)out)[NB * NCAND + b] = f2bf(v);
      }
    }
    return;
  }

  // ================= actor role =================
  const int b = blockIdx.x / 7;
  const int cb = blockIdx.x % 7;
  const int cbase = cb * 29;
  const int cntc = min(29, NCAND - cbase);
  const int F6 = F[6], F8 = F[8], F9 = F[9], F10 = F[10];

  // ---- local pact (bit-identical replication of the old pp role) ----
  {
    float ssum = 0.f, smax = 0.f;
    if (t < 128) {
#pragma unroll
      for (int sl = 0; sl < 16; ++sl) {
        ssum += psumP[((long)b * 16 + sl) * 128 + t];
        smax = fmaxf(smax, pmaxP[((long)b * 16 + sl) * 128 + t]);
      }
      plf[t] = bf2f(f2bf(ssum * (1.0f / 10000.0f)));  // match actor bf16 quant
      plf[128 + t] = bf2f(f2bf(smax));
    }
    __syncthreads();
    float a = gld(ab1, t, F6);
    const unsigned short* row = aw1t + t * 384 + 128;
#pragma unroll
    for (int k8 = 0; k8 < 32; ++k8) {
      short8 w = *(const short8*)(row + k8 * 8);
#pragma unroll
      for (int j = 0; j < 8; ++j)
        a += plf[k8 * 8 + j] * bf2f((unsigned short)w[j]);
    }
    pactS[t] = a;
  }

  // actor layer 1 (candidate part): [32 x 128] @ [128 x 256] + pact
  {
    f32x4 acc[2][4];
#pragma unroll
    for (int mt = 0; mt < 2; ++mt)
#pragma unroll
      for (int nt = 0; nt < 4; ++nt) acc[mt][nt] = (f32x4){0.f, 0.f, 0.f, 0.f};
    const unsigned short* cfb = cfw + (long)blockIdx.x * 4096;
#pragma unroll
    for (int ks = 0; ks < 4; ++ks) {
      short8 af0 = *(const short8*)(cfb + (lane & 15) * 128 + ks * 32 + ((lane >> 4) * 8));
      short8 af1 = *(const short8*)(cfb + (16 + (lane & 15)) * 128 + ks * 32 + ((lane >> 4) * 8));
#pragma unroll
      for (int nt = 0; nt < 4; ++nt) {
        int col = wv * 64 + nt * 16 + (lane & 15);
        short8 bfr = *(const short8*)(aw1t + col * 384 + ks * 32 + ((lane >> 4) * 8));
        acc[0][nt] = __builtin_amdgcn_mfma_f32_16x16x32_bf16(af0, bfr, acc[0][nt], 0, 0, 0);
        acc[1][nt] = __builtin_amdgcn_mfma_f32_16x16x32_bf16(af1, bfr, acc[1][nt], 0, 0, 0);
      }
    }
    __syncthreads();  // pactS complete before epilogue reads
#pragma unroll
    for (int mt = 0; mt < 2; ++mt)
#pragma unroll
      for (int nt = 0; nt < 4; ++nt) {
        int col = wv * 64 + nt * 16 + (lane & 15);
        float bb = pactS[col];
#pragma unroll
        for (int r = 0; r < 4; ++r) {
          int row = mt * 16 + ((lane >> 4) * 4) + r;
          a1s[row * 264 + col] = f2bf(fast_tanh(acc[mt][nt][r] + bb));
        }
      }
  }
  __syncthreads();

  // actor layer 2: [32 x 256] @ [256 x 256]
  {
    f32x4 acc[2][4];
#pragma unroll
    for (int mt = 0; mt < 2; ++mt)
#pragma unroll
      for (int nt = 0; nt < 4; ++nt) acc[mt][nt] = (f32x4){0.f, 0.f, 0.f, 0.f};
    for (int ks = 0; ks < 8; ++ks) {
      short8 af0 = *(const short8*)(a1s + (lane & 15) * 264 + ks * 32 + ((lane >> 4) * 8));
      short8 af1 = *(const short8*)(a1s + (16 + (lane & 15)) * 264 + ks * 32 + ((lane >> 4) * 8));
#pragma unroll
      for (int nt = 0; nt < 4; ++nt) {
        int col = wv * 64 + nt * 16 + (lane & 15);
        short8 bfr = *(const short8*)(aw2t + col * 256 + ks * 32 + ((lane >> 4) * 8));
        acc[0][nt] = __builtin_amdgcn_mfma_f32_16x16x32_bf16(af0, bfr, acc[0][nt], 0, 0, 0);
        acc[1][nt] = __builtin_amdgcn_mfma_f32_16x16x32_bf16(af1, bfr, acc[1][nt], 0, 0, 0);
      }
    }
    float ab2v = gld(ab2, t, F8);
    ((float*)plf)[t] = ab2v;   // reuse plf as ab2 cache
    __syncthreads();
#pragma unroll
    for (int mt = 0; mt < 2; ++mt)
#pragma unroll
      for (int nt = 0; nt < 4; ++nt) {
        int col = wv * 64 + nt * 16 + (lane & 15);
        float bb = plf[col];
#pragma unroll
        for (int r = 0; r < 4; ++r) {
          int row = mt * 16 + ((lane >> 4) * 4) + r;
          a2s[row * 264 + col] = f2bf(fast_tanh(acc[mt][nt][r] + bb));
        }
      }
  }
  __syncthreads();

  // layer 3: per-row dot-256 with a_w3 -> scores (device-scope atomicExch)
  {
    int row = t >> 3, seg = t & 7;
    float p = 0.f;
#pragma unroll 8
    for (int i = 0; i < 32; ++i) {
      int k = seg * 32 + i;
      p += bf2f(a2s[row * 264 + k]) * gld(aw3, k, F9);
    }
    p += __shfl_xor(p, 1);
    p += __shfl_xor(p, 2);
    p += __shfl_xor(p, 4);
    if (seg == 0 && row < cntc)
      atomicExch(&scores[b * 256 + cbase + row], p + gld(ab3, 0, F10));
  }
  __syncthreads();

  if (t == 0) {
    __threadfence();
    amLast = (atomicAdd(&scnt[b], 1) == 6);
  }
  __syncthreads();
  if (!amLast) return;

  // ---- masked softmax tail (last cand-block of this batch) ----
  const int MM = F[17];
  const int OF = (F[0] + F[1] + F[3] + F[5] + F[7] + F[9] + F[11] + F[13] + F[15]) >= 5;
  float sraw = 0.f, sv = -1e30f;
  bool valid = false;
  if (t < NCAND) {
    sraw = atomicAdd(&scores[b * 256 + t], 0.0f);   // coherent read
    long idx = (long)b * NCAND + t;
    if (MM == 0)      valid = ((const int*)mask)[idx] != 0;
    else if (MM == 1) valid = ((const unsigned char*)mask)[idx] != 0;
    else if (MM == 2) valid = ((const unsigned short*)mask)[idx] != 0;
    else              valid = ((const unsigned int*)mask)[idx] != 0;
    if (valid) sv = sraw;
  }
  float m = sv;
  for (int o = 32; o; o >>= 1) m = fmaxf(m, __shfl_xor(m, o));
  if (lane == 0) red[wv] = m;
  __syncthreads();
  m = fmaxf(fmaxf(red[0], red[1]), fmaxf(red[2], red[3]));
  __syncthreads();
  float e = valid ? __expf(sraw - m) : 0.f;
  if (!(e == e)) e = 0.f;  // scrub
  float ss = e;
  for (int o = 32; o; o >>= 1) ss += __shfl_xor(ss, o);
  if (lane == 0) red[wv] = ss;
  __syncthreads();
  float tot = red[0] + red[1] + red[2] + red[3];
  tot = fmaxf(tot, 1e-30f);
  if (t < NCAND) {
    float pv = e / tot;
    if (!(pv == pv)) pv = 0.f;  // scrub
    if (OF) ((float*)out)[b * NCAND + t] = pv;
    else ((unsigned short*)out)[b * NCAND + t] = f2bf(pv);
  }
}

// ---------------------------------------------------------------------------
extern "C" void kernel_launch(void* const* d_in, const int* in_sizes, int n_in,
                              void* d_out, int out_size, void* d_ws, size_t ws_size,
                              hipStream_t stream) {
  const void* x = d_in[0];
  const int* cand = (const int*)d_in[1];
  const void* mask = d_in[2];
  const void* fe_w1 = d_in[3];
  const void* fe_b1 = d_in[4];
  const void* fe_w2 = d_in[5];
  const void* fe_b2 = d_in[6];
  const void* a_w1 = d_in[7];
  const void* a_b1 = d_in[8];
  const void* a_w2 = d_in[9];
  const void* a_b2 = d_in[10];
  const void* a_w3 = d_in[11];
  const void* a_b3 = d_in[12];
  const void* c_w1 = d_in[13];
  const void* c_b1 = d_in[14];
  const void* c_w2 = d_in[15];
  const void* c_b2 = d_in[16];
  const void* c_w3 = d_in[17];
  const void* c_b3 = d_in[18];

  char* ws = (char*)d_ws;
  float* scores = (float*)(ws + 65536);                   // 64*256 f32
  unsigned short* aw1t = (unsigned short*)(ws + 147456);  // 256*384 bf16
  unsigned short* aw2t = (unsigned short*)(ws + 344064);  // 256*256 bf16
  int* F = (int*)(ws + 475136);                           // 20 ints
  unsigned short* cw1t = (unsigned short*)(ws + 475264);  // 256*256 bf16
  unsigned short* cw2t = (unsigned short*)(ws + 606336);  // 256*256 bf16
  unsigned short* cfw = (unsigned short*)(ws + 802944);   // 448*4096 bf16
  int* scnt = (int*)(ws + 4472960);                       // 64 ints
  float* psumP = (float*)(ws + 4473216);                  // 64*16*128 f32
  float* pmaxP = (float*)(ws + 4997504);                  // 64*16*128 f32 (ends 5521792)

  mega_kernel<<<1875, 256, 0, stream>>>(x, cand, fe_w1, fe_b1, fe_w2, fe_b2,
                                        a_w1, a_b1, a_w2, a_b2, a_w3, a_b3,
                                        c_w1, c_b1, c_w2, c_b2, c_w3, c_b3,
                                        (const unsigned int*)mask,
                                        (const unsigned int*)cand, F, scnt,
                                        psumP, pmaxP, cfw, aw1t, aw2t, cw1t, cw2t);
  actorBC_kernel<<<512, 256, 0, stream>>>(cfw, a_b1, a_b2, a_w3, a_b3, mask, F,
                                          psumP, pmaxP, aw1t, aw2t, cw1t, cw2t,
                                          c_b1, c_b2, c_w3, c_b3,
                                          scores, scnt, (void*)d_out);
}

// Round 15
// 160.674 us; speedup vs baseline: 1.0378x; 1.0378x over previous
//
#include <hip/hip_runtime.h>

#define NN 10000
#define NCAND 201
#define NB 64

typedef __attribute__((ext_vector_type(8))) short short8;
typedef __attribute__((ext_vector_type(4))) float f32x4;

__device__ __forceinline__ float bf2f(unsigned short u) {
  return __uint_as_float(((unsigned int)u) << 16);
}
__device__ __forceinline__ unsigned short f2bf(float f) {
  unsigned int u = __float_as_uint(f);
  u += 0x7FFFu + ((u >> 16) & 1u);   // RNE
  return (unsigned short)(u >> 16);
}
__device__ __forceinline__ float fast_tanh(float x) {
  return 1.0f - 2.0f / (__expf(2.0f * x) + 1.0f);
}
// generic load: flag=1 -> float32 array, flag=0 -> bf16 array
__device__ __forceinline__ float gld(const void* p, long i, int f) {
  return f ? ((const float*)p)[i] : bf2f(((const unsigned short*)p)[i]);
}

// ---------------------------------------------------------------------------
// MEGA launch (everything with no intra-launch dependencies):
//  [0,1024)    : feat_pool role -- atomic-free partial pooling into
//                psumP/pmaxP[(b*16+s)*128+col] (no zero-init dependency).
//  [1024,1472) : actorA role -- candidate h1 -> layer2 features cf -> cfw.
//  [1472,1856) : transpose aw1t/aw2t/cw1t/cw2t (256-sample self-detect).
//  [1856,1873) : F[j] per-array f32 flags.  1873: mask mode.  1874: cand
//                width + zero scnt.
// R14 lesson: do NOT fold pp/critic into actorB -- the replicated pact
// projection pushed VGPR to 196 (occupancy cliff) and regressed 5 us.
// ---------------------------------------------------------------------------
__global__ __launch_bounds__(256, 4)
void mega_kernel(const void* __restrict__ x, const int* __restrict__ cand,
                 const void* w1, const void* b1, const void* w2, const void* b2,
                 const void* aw1, const void* ab1, const void* aw2, const void* ab2,
                 const void* aw3, const void* ab3,
                 const void* cw1, const void* cb1, const void* cw2, const void* cb2,
                 const void* cw3, const void* cb3,
                 const unsigned int* mask_w, const unsigned int* cand_w,
                 int* F, int* scnt,
                 float* __restrict__ psumP, float* __restrict__ pmaxP,
                 unsigned short* __restrict__ cfw,
                 unsigned short* __restrict__ aw1t, unsigned short* __restrict__ aw2t,
                 unsigned short* __restrict__ cw1t, unsigned short* __restrict__ cw2t) {
  __shared__ __align__(16) unsigned short pool[128 * 72];  // 18432 B overlay
  __shared__ float w1f[3 * 64];
  __shared__ float b1f[64];
  __shared__ float b2f[128];
  __shared__ int cnts[8];

  const int t = threadIdx.x;
  const int j = blockIdx.x;
  const int lane = t & 63;
  const int wv = t >> 6;

  if (j < 1472) {
    // ---- shared self-detect for fp/actorA roles: x,w1,b1,b2,w2,cand ----
    if (t < 8) cnts[t] = 0;
    __syncthreads();
    {
      if ((((const unsigned short*)x)[t] & 0x7F80u) >= 0x4300u) atomicAdd(&cnts[0], 1);
      if (t < 192 && (((const unsigned short*)w1)[t] & 0x7F80u) >= 0x4300u) atomicAdd(&cnts[1], 1);
      if (t < 64 && (((const unsigned short*)b1)[t] & 0x7F80u) >= 0x4300u) atomicAdd(&cnts[2], 1);
      if (t < 128 && (((const unsigned short*)b2)[t] & 0x7F80u) >= 0x4300u) atomicAdd(&cnts[3], 1);
      if ((((const unsigned short*)w2)[t] & 0x7F80u) >= 0x4300u) atomicAdd(&cnts[4], 1);
      int co = 0;
#pragma unroll
      for (int q = 0; q < 4; ++q) {
        int i = t * 4 + q;
        if ((i & 1) && cand_w[i] != 0u) co = 1;
      }
      if (co) atomicAdd(&cnts[5], 1);
    }
    __syncthreads();
    const int F0 = cnts[0] > 32, F1 = cnts[1] > 24, F2 = cnts[2] > 8;
    const int F4 = cnts[3] > 16, Fw2 = cnts[4] > 32, C64 = cnts[5] == 0;

    if (j < 1024) {
      // ================= feat_pool role =================
      unsigned short* h1s = pool;  // [128][72]
      const int b = j >> 4;
      const int s = j & 15;

      if (t < 192) w1f[t] = gld(w1, t, F1);
      if (t < 64) b1f[t] = gld(b1, t, F2);
      if (t < 128) b2f[t] = gld(b2, t, F4);

      // B fragments gathered from fe_w2 [k][n] (strided scalar, once/block)
      short8 bfr[2][2];
#pragma unroll
      for (int nl = 0; nl < 2; ++nl)
#pragma unroll
        for (int ks = 0; ks < 2; ++ks) {
          int col = wv * 32 + nl * 16 + (lane & 15);
          short8 v;
#pragma unroll
          for (int jj = 0; jj < 8; ++jj) {
            int k = (lane >> 4) * 8 + ks * 32 + jj;
            v[jj] = (short)f2bf(gld(w2, (long)k * 128 + col, Fw2));
          }
          bfr[nl][ks] = v;
        }
      __syncthreads();

      float csum[2] = {0.f, 0.f};
      float cmax[2] = {0.f, 0.f};
      const int m = t & 127;
      const int kg = t >> 7;

      float x0 = 0.f, x1 = 0.f, x2 = 0.f;
      if (s < 79) {
        int nb = s * 128;
        if (m < min(128, NN - nb)) {
          long xo = ((long)b * NN + nb + m) * 3;
          x0 = gld(x, xo, F0); x1 = gld(x, xo + 1, F0); x2 = gld(x, xo + 2, F0);
        }
      }

      for (int c = s; c < 79; c += 16) {
        int nb = c * 128;
        int cnt = (nb + 128 <= NN) ? 128 : (NN - nb);
        if (m < cnt) {
#pragma unroll
          for (int blk = 0; blk < 4; ++blk) {
            short8 v;
#pragma unroll
            for (int i = 0; i < 8; ++i) {
              int k = kg * 32 + blk * 8 + i;
              float vv = x0 * w1f[k] + x1 * w1f[64 + k] + x2 * w1f[128 + k] + b1f[k];
              v[i] = (short)f2bf(fmaxf(vv, 0.f));
            }
            *(short8*)(h1s + m * 72 + kg * 32 + blk * 8) = v;
          }
        }
        {
          int cn = c + 16;
          float nx0 = 0.f, nx1 = 0.f, nx2 = 0.f;
          if (cn < 79) {
            int nbn = cn * 128;
            if (m < min(128, NN - nbn)) {
              long xo = ((long)b * NN + nbn + m) * 3;
              nx0 = gld(x, xo, F0); nx1 = gld(x, xo + 1, F0); nx2 = gld(x, xo + 2, F0);
            }
          }
          __syncthreads();
          x0 = nx0; x1 = nx1; x2 = nx2;
        }
#pragma unroll
        for (int mt = 0; mt < 8; ++mt) {
          const unsigned short* ap = h1s + (mt * 16 + (lane & 15)) * 72 + ((lane >> 4) * 8);
          short8 af0 = *(const short8*)(ap);
          short8 af1 = *(const short8*)(ap + 32);
#pragma unroll
          for (int nl = 0; nl < 2; ++nl) {
            f32x4 acc = {0.f, 0.f, 0.f, 0.f};
            acc = __builtin_amdgcn_mfma_f32_16x16x32_bf16(af0, bfr[nl][0], acc, 0, 0, 0);
            acc = __builtin_amdgcn_mfma_f32_16x16x32_bf16(af1, bfr[nl][1], acc, 0, 0, 0);
            int col = wv * 32 + nl * 16 + (lane & 15);
            float bb = b2f[col];
#pragma unroll
            for (int r = 0; r < 4; ++r) {
              int row = mt * 16 + ((lane >> 4) * 4) + r;
              if (row < cnt) {
                float v = fmaxf(acc[r] + bb, 0.f);
                csum[nl] += v;
                cmax[nl] = fmaxf(cmax[nl], v);
              }
            }
          }
        }
        __syncthreads();
      }
#pragma unroll
      for (int nl = 0; nl < 2; ++nl) {
        csum[nl] += __shfl_xor(csum[nl], 16);
        csum[nl] += __shfl_xor(csum[nl], 32);
        cmax[nl] = fmaxf(cmax[nl], __shfl_xor(cmax[nl], 16));
        cmax[nl] = fmaxf(cmax[nl], __shfl_xor(cmax[nl], 32));
      }
      if (lane < 16) {
#pragma unroll
        for (int nl = 0; nl < 2; ++nl) {
          int col = wv * 32 + nl * 16 + lane;
          psumP[((long)b * 16 + s) * 128 + col] = csum[nl];   // plain stores
          pmaxP[((long)b * 16 + s) * 128 + col] = cmax[nl];
        }
      }
    } else {
      // ================= actorA role: h1c -> cf -> cfw =================
      unsigned short* h1c = pool;           // [32][72]
      const int idx = j - 1024;
      const int b = idx / 7;
      const int cb = idx % 7;
      const int cbase = cb * 29;

      if (t < 128) b2f[t] = gld(b2, t, F4);

      {
        int r = t & 31;
        int ci = cbase + r;
        if (ci > NCAND - 1) ci = NCAND - 1;
        long cidx = (long)b * NCAND + ci;
        int nd = C64 ? cand[2 * cidx] : cand[cidx];
        long xo = ((long)b * NN + nd) * 3;
        float x0 = gld(x, xo, F0), x1 = gld(x, xo + 1, F0), x2 = gld(x, xo + 2, F0);
        int kg = t >> 5;
#pragma unroll
        for (int i = 0; i < 8; ++i) {
          int k = kg * 8 + i;
          float v = x0 * gld(w1, k, F1) + x1 * gld(w1, 64 + k, F1) +
                    x2 * gld(w1, 128 + k, F1) + gld(b1, k, F2);
          h1c[r * 72 + k] = f2bf(fmaxf(v, 0.f));
        }
      }
      __syncthreads();

      {
        short8 af[2][2];
#pragma unroll
        for (int mt = 0; mt < 2; ++mt)
#pragma unroll
          for (int ks = 0; ks < 2; ++ks)
            af[mt][ks] = *(const short8*)(h1c + (mt * 16 + (lane & 15)) * 72 + ((lane >> 4) * 8) + ks * 32);
#pragma unroll
        for (int nl = 0; nl < 2; ++nl) {
          int col = wv * 32 + nl * 16 + (lane & 15);
          short8 bf0, bf1;
#pragma unroll
          for (int jj = 0; jj < 8; ++jj) {
            int k = (lane >> 4) * 8 + jj;
            bf0[jj] = (short)f2bf(gld(w2, (long)k * 128 + col, Fw2));
            bf1[jj] = (short)f2bf(gld(w2, (long)(k + 32) * 128 + col, Fw2));
          }
          float bb = b2f[col];
#pragma unroll
          for (int mt = 0; mt < 2; ++mt) {
            f32x4 acc = {0.f, 0.f, 0.f, 0.f};
            acc = __builtin_amdgcn_mfma_f32_16x16x32_bf16(af[mt][0], bf0, acc, 0, 0, 0);
            acc = __builtin_amdgcn_mfma_f32_16x16x32_bf16(af[mt][1], bf1, acc, 0, 0, 0);
#pragma unroll
            for (int r = 0; r < 4; ++r) {
              int row = mt * 16 + ((lane >> 4) * 4) + r;
              cfw[(long)idx * 4096 + row * 128 + col] = f2bf(fmaxf(acc[r] + bb, 0.f));
            }
          }
        }
      }
    }
    return;
  }

  // ---- housekeeping roles ----
  if (t < 8) cnts[t] = 0;
  __syncthreads();

  if (j < 1856) {
    const unsigned short* pa = (const unsigned short*)aw1;
    const unsigned short* pb = (const unsigned short*)aw2;
    const unsigned short* pc = (const unsigned short*)cw1;
    const unsigned short* pd = (const unsigned short*)cw2;
    if ((pa[t] & 0x7F80u) >= 0x4300u) atomicAdd(&cnts[0], 1);
    if ((pb[t] & 0x7F80u) >= 0x4300u) atomicAdd(&cnts[1], 1);
    if ((pc[t] & 0x7F80u) >= 0x4300u) atomicAdd(&cnts[2], 1);
    if ((pd[t] & 0x7F80u) >= 0x4300u) atomicAdd(&cnts[3], 1);
    __syncthreads();
    const int Faw1 = cnts[0] > 32, Faw2 = cnts[1] > 32;
    const int Fcw1 = cnts[2] > 32, Fcw2 = cnts[3] > 32;
    int i = (j - 1472) * 256 + t;
    if (i < 256 * 384) { int n = i / 384, k = i % 384; aw1t[i] = f2bf(gld(aw1, k * 256 + n, Faw1)); }
    if (i < 256 * 256) {
      int n = i >> 8, k = i & 255;
      aw2t[i] = f2bf(gld(aw2, k * 256 + n, Faw2));
      cw1t[i] = f2bf(gld(cw1, k * 256 + n, Fcw1));
      cw2t[i] = f2bf(gld(cw2, k * 256 + n, Fcw2));
    }
  } else if (j < 1873) {
    const void* ptrs[17] = {x, w1, b1, w2, b2, aw1, ab1, aw2, ab2, aw3, ab3,
                            cw1, cb1, cw2, cb2, cw3, cb3};
    const int sizes[17] = {1920000, 192, 64, 8192, 128, 98304, 256, 65536, 256,
                           256, 1, 65536, 256, 65536, 256, 256, 1};
    int a = j - 1856;
    const unsigned short* p = (const unsigned short*)ptrs[a];
    int K = min(sizes[a], 2048);
    int c = 0;
    for (int i = t; i < K; i += 256)
      if ((p[i] & 0x7F80u) >= 0x4300u) c++;
    if (c) atomicAdd(&cnts[0], c);
    __syncthreads();
    if (t == 0) F[a] = (cnts[0] > (K >> 3)) ? 1 : 0;
  } else if (j == 1873) {
    int flo = 0, fhi = 0, fgt = 0;
    for (int i = t; i < 3216; i += 256) {
      unsigned int w = mask_w[i];
      if ((w & 0xFFFFu) == 0x3F80u) flo = 1;
      if ((w >> 16) == 0x3F80u) fhi = 1;
      if (w > 1u) fgt = 1;
    }
    if (flo) cnts[0] = 1;
    if (fhi) cnts[1] = 1;
    if (fgt) cnts[2] = 1;
    __syncthreads();
    if (t == 0) F[17] = cnts[0] ? 2 : (cnts[1] ? 3 : (cnts[2] ? 1 : 0));
  } else {
    int co = 0;
    for (int i = t; i < 1024; i += 256)
      if ((i & 1) && cand_w[i] != 0u) co = 1;
    if (co) cnts[0] = 1;
    if (t < 64) scnt[t] = 0;
    __syncthreads();
    if (t == 0) F[18] = cnts[0] ? 0 : 1;
  }
}

// ---------------------------------------------------------------------------
// blocks 0..63: pooled projection -> pact; blocks 64..127: critic -> v
// both reduce the 16 per-slice pooling partials (deterministic order)
// ---------------------------------------------------------------------------
__global__ __launch_bounds__(256)
void pp_critic_kernel(const float* __restrict__ psumP, const float* __restrict__ pmaxP,
                      const unsigned short* __restrict__ aw1t,
                      const void* __restrict__ ab1,
                      const unsigned short* __restrict__ cw1t,
                      const unsigned short* __restrict__ cw2t,
                      const void* __restrict__ cb1, const void* __restrict__ cb2,
                      const void* __restrict__ cw3, const void* __restrict__ cb3,
                      const int* __restrict__ F,
                      float* __restrict__ pact, void* __restrict__ out) {
  __shared__ float plf[256];
  __shared__ float c1f[256];
  __shared__ float red[4];
  const int t = threadIdx.x;
  const int b = blockIdx.x & 63;
  const int lane = t & 63, wv = t >> 6;

  float ssum = 0.f, smax = 0.f;
  if (t < 128) {
#pragma unroll
    for (int sl = 0; sl < 16; ++sl) {
      ssum += psumP[((long)b * 16 + sl) * 128 + t];
      smax = fmaxf(smax, pmaxP[((long)b * 16 + sl) * 128 + t]);
    }
  }

  if (blockIdx.x < 64) {
    const int F6 = F[6];
    if (t < 128) {
      plf[t] = bf2f(f2bf(ssum * (1.0f / 10000.0f)));  // match actor bf16 quant
      plf[128 + t] = bf2f(f2bf(smax));
    }
    __syncthreads();
    float a = gld(ab1, t, F6);
    const unsigned short* row = aw1t + t * 384 + 128;
#pragma unroll
    for (int k8 = 0; k8 < 32; ++k8) {
      short8 w = *(const short8*)(row + k8 * 8);
#pragma unroll
      for (int j = 0; j < 8; ++j)
        a += plf[k8 * 8 + j] * bf2f((unsigned short)w[j]);
    }
    pact[b * 256 + t] = a;
  } else {
    const int OF = (F[0] + F[1] + F[3] + F[5] + F[7] + F[9] + F[11] + F[13] + F[15]) >= 5;
    const int F12 = F[12], F14 = F[14], F15 = F[15], F16 = F[16];
    if (t < 128) {
      plf[t] = ssum * (1.0f / 10000.0f);
      plf[128 + t] = smax;
    }
    __syncthreads();
    {
      float a = gld(cb1, t, F12);
      const unsigned short* row = cw1t + t * 256;
#pragma unroll
      for (int k8 = 0; k8 < 32; ++k8) {
        short8 w = *(const short8*)(row + k8 * 8);
#pragma unroll
        for (int j = 0; j < 8; ++j)
          a += plf[k8 * 8 + j] * bf2f((unsigned short)w[j]);
      }
      c1f[t] = fast_tanh(a);
    }
    __syncthreads();
    {
      float a2 = gld(cb2, t, F14);
      const unsigned short* row = cw2t + t * 256;
#pragma unroll
      for (int k8 = 0; k8 < 32; ++k8) {
        short8 w = *(const short8*)(row + k8 * 8);
#pragma unroll
        for (int j = 0; j < 8; ++j)
          a2 += c1f[k8 * 8 + j] * bf2f((unsigned short)w[j]);
      }
      a2 = fast_tanh(a2);
      float p = a2 * gld(cw3, t, F15);
      for (int o = 32; o; o >>= 1) p += __shfl_xor(p, o);
      __syncthreads();
      if (lane == 0) red[wv] = p;
      __syncthreads();
      if (t == 0) {
        float v = red[0] + red[1] + red[2] + red[3] + gld(cb3, 0, F16);
        if (!(v == v)) v = 0.f;  // scrub
        if (OF) ((float*)out)[NB * NCAND + b] = v;
        else ((unsigned short*)out)[NB * NCAND + b] = f2bf(v);
      }
    }
  }
}

// ---------------------------------------------------------------------------
// actorB: layers 1-3 from cfw + pact -> scores; the LAST cand-block of each
// batch (per-batch counter) runs the masked softmax. scores via device-scope
// atomicExch; tail reads via atomicAdd(p,0) -- coherent across XCDs (G16).
// ---------------------------------------------------------------------------
__global__ __launch_bounds__(256)
void actorB_kernel(const unsigned short* __restrict__ cfw,
                   const void* __restrict__ ab2,
                   const void* __restrict__ aw3, const void* __restrict__ ab3,
                   const void* __restrict__ mask,
                   const int* __restrict__ F,
                   const float* __restrict__ pact,
                   const unsigned short* __restrict__ aw1t,
                   const unsigned short* __restrict__ aw2t,
                   float* __restrict__ scores, int* __restrict__ scnt,
                   void* __restrict__ out) {
  __shared__ __align__(16) unsigned short a1s[32 * 264];
  __shared__ __align__(16) unsigned short a2s[32 * 264];
  __shared__ float pactS[256], ab2f[256];
  __shared__ float red[4];
  __shared__ int amLast;

  const int t = threadIdx.x;
  const int b = blockIdx.x / 7;
  const int cb = blockIdx.x % 7;
  const int cbase = cb * 29;
  const int cntc = min(29, NCAND - cbase);
  const int lane = t & 63;
  const int wv = t >> 6;
  const int F8 = F[8], F9 = F[9], F10 = F[10];

  pactS[t] = pact[b * 256 + t];
  ab2f[t] = gld(ab2, t, F8);

  // actor layer 1 (candidate part): [32 x 128] @ [128 x 256] + pact
  {
    f32x4 acc[2][4];
#pragma unroll
    for (int mt = 0; mt < 2; ++mt)
#pragma unroll
      for (int nt = 0; nt < 4; ++nt) acc[mt][nt] = (f32x4){0.f, 0.f, 0.f, 0.f};
    const unsigned short* cfb = cfw + (long)blockIdx.x * 4096;
#pragma unroll
    for (int ks = 0; ks < 4; ++ks) {
      short8 af0 = *(const short8*)(cfb + (lane & 15) * 128 + ks * 32 + ((lane >> 4) * 8));
      short8 af1 = *(const short8*)(cfb + (16 + (lane & 15)) * 128 + ks * 32 + ((lane >> 4) * 8));
#pragma unroll
      for (int nt = 0; nt < 4; ++nt) {
        int col = wv * 64 + nt * 16 + (lane & 15);
        short8 bfr = *(const short8*)(aw1t + col * 384 + ks * 32 + ((lane >> 4) * 8));
        acc[0][nt] = __builtin_amdgcn_mfma_f32_16x16x32_bf16(af0, bfr, acc[0][nt], 0, 0, 0);
        acc[1][nt] = __builtin_amdgcn_mfma_f32_16x16x32_bf16(af1, bfr, acc[1][nt], 0, 0, 0);
      }
    }
    __syncthreads();
#pragma unroll
    for (int mt = 0; mt < 2; ++mt)
#pragma unroll
      for (int nt = 0; nt < 4; ++nt) {
        int col = wv * 64 + nt * 16 + (lane & 15);
        float bb = pactS[col];
#pragma unroll
        for (int r = 0; r < 4; ++r) {
          int row = mt * 16 + ((lane >> 4) * 4) + r;
          a1s[row * 264 + col] = f2bf(fast_tanh(acc[mt][nt][r] + bb));
        }
      }
  }
  __syncthreads();

  // actor layer 2: [32 x 256] @ [256 x 256]
  {
    f32x4 acc[2][4];
#pragma unroll
    for (int mt = 0; mt < 2; ++mt)
#pragma unroll
      for (int nt = 0; nt < 4; ++nt) acc[mt][nt] = (f32x4){0.f, 0.f, 0.f, 0.f};
    for (int ks = 0; ks < 8; ++ks) {
      short8 af0 = *(const short8*)(a1s + (lane & 15) * 264 + ks * 32 + ((lane >> 4) * 8));
      short8 af1 = *(const short8*)(a1s + (16 + (lane & 15)) * 264 + ks * 32 + ((lane >> 4) * 8));
#pragma unroll
      for (int nt = 0; nt < 4; ++nt) {
        int col = wv * 64 + nt * 16 + (lane & 15);
        short8 bfr = *(const short8*)(aw2t + col * 256 + ks * 32 + ((lane >> 4) * 8));
        acc[0][nt] = __builtin_amdgcn_mfma_f32_16x16x32_bf16(af0, bfr, acc[0][nt], 0, 0, 0);
        acc[1][nt] = __builtin_amdgcn_mfma_f32_16x16x32_bf16(af1, bfr, acc[1][nt], 0, 0, 0);
      }
    }
#pragma unroll
    for (int mt = 0; mt < 2; ++mt)
#pragma unroll
      for (int nt = 0; nt < 4; ++nt) {
        int col = wv * 64 + nt * 16 + (lane & 15);
        float bb = ab2f[col];
#pragma unroll
        for (int r = 0; r < 4; ++r) {
          int row = mt * 16 + ((lane >> 4) * 4) + r;
          a2s[row * 264 + col] = f2bf(fast_tanh(acc[mt][nt][r] + bb));
        }
      }
  }
  __syncthreads();

  // layer 3: per-row dot-256 with a_w3 -> scores (device-scope atomicExch)
  {
    int row = t >> 3, seg = t & 7;
    float p = 0.f;
#pragma unroll 8
    for (int i = 0; i < 32; ++i) {
      int k = seg * 32 + i;
      p += bf2f(a2s[row * 264 + k]) * gld(aw3, k, F9);
    }
    p += __shfl_xor(p, 1);
    p += __shfl_xor(p, 2);
    p += __shfl_xor(p, 4);
    if (seg == 0 && row < cntc)
      atomicExch(&scores[b * 256 + cbase + row], p + gld(ab3, 0, F10));
  }
  __syncthreads();

  if (t == 0) {
    __threadfence();
    amLast = (atomicAdd(&scnt[b], 1) == 6);
  }
  __syncthreads();
  if (!amLast) return;

  // ---- masked softmax tail (last cand-block of this batch) ----
  const int MM = F[17];
  const int OF = (F[0] + F[1] + F[3] + F[5] + F[7] + F[9] + F[11] + F[13] + F[15]) >= 5;
  float sraw = 0.f, sv = -1e30f;
  bool valid = false;
  if (t < NCAND) {
    sraw = atomicAdd(&scores[b * 256 + t], 0.0f);   // coherent read
    long idx = (long)b * NCAND + t;
    if (MM == 0)      valid = ((const int*)mask)[idx] != 0;
    else if (MM == 1) valid = ((const unsigned char*)mask)[idx] != 0;
    else if (MM == 2) valid = ((const unsigned short*)mask)[idx] != 0;
    else              valid = ((const unsigned int*)mask)[idx] != 0;
    if (valid) sv = sraw;
  }
  float m = sv;
  for (int o = 32; o; o >>= 1) m = fmaxf(m, __shfl_xor(m, o));
  if (lane == 0) red[wv] = m;
  __syncthreads();
  m = fmaxf(fmaxf(red[0], red[1]), fmaxf(red[2], red[3]));
  __syncthreads();
  float e = valid ? __expf(sraw - m) : 0.f;
  if (!(e == e)) e = 0.f;  // scrub
  float ss = e;
  for (int o = 32; o; o >>= 1) ss += __shfl_xor(ss, o);
  if (lane == 0) red[wv] = ss;
  __syncthreads();
  float tot = red[0] + red[1] + red[2] + red[3];
  tot = fmaxf(tot, 1e-30f);
  if (t < NCAND) {
    float pv = e / tot;
    if (!(pv == pv)) pv = 0.f;  // scrub
    if (OF) ((float*)out)[b * NCAND + t] = pv;
    else ((unsigned short*)out)[b * NCAND + t] = f2bf(pv);
  }
}

// ---------------------------------------------------------------------------
extern "C" void kernel_launch(void* const* d_in, const int* in_sizes, int n_in,
                              void* d_out, int out_size, void* d_ws, size_t ws_size,
                              hipStream_t stream) {
  const void* x = d_in[0];
  const int* cand = (const int*)d_in[1];
  const void* mask = d_in[2];
  const void* fe_w1 = d_in[3];
  const void* fe_b1 = d_in[4];
  const void* fe_w2 = d_in[5];
  const void* fe_b2 = d_in[6];
  const void* a_w1 = d_in[7];
  const void* a_b1 = d_in[8];
  const void* a_w2 = d_in[9];
  const void* a_b2 = d_in[10];
  const void* a_w3 = d_in[11];
  const void* a_b3 = d_in[12];
  const void* c_w1 = d_in[13];
  const void* c_b1 = d_in[14];
  const void* c_w2 = d_in[15];
  const void* c_b2 = d_in[16];
  const void* c_w3 = d_in[17];
  const void* c_b3 = d_in[18];

  char* ws = (char*)d_ws;
  float* scores = (float*)(ws + 65536);                   // 64*256 f32
  unsigned short* aw1t = (unsigned short*)(ws + 147456);  // 256*384 bf16
  unsigned short* aw2t = (unsigned short*)(ws + 344064);  // 256*256 bf16
  int* F = (int*)(ws + 475136);                           // 20 ints
  unsigned short* cw1t = (unsigned short*)(ws + 475264);  // 256*256 bf16
  unsigned short* cw2t = (unsigned short*)(ws + 606336);  // 256*256 bf16
  float* pact = (float*)(ws + 737408);                    // 64*256 f32
  unsigned short* cfw = (unsigned short*)(ws + 802944);   // 448*4096 bf16
  int* scnt = (int*)(ws + 4472960);                       // 64 ints
  float* psumP = (float*)(ws + 4473216);                  // 64*16*128 f32
  float* pmaxP = (float*)(ws + 4997504);                  // 64*16*128 f32 (ends 5521792)

  mega_kernel<<<1875, 256, 0, stream>>>(x, cand, fe_w1, fe_b1, fe_w2, fe_b2,
                                        a_w1, a_b1, a_w2, a_b2, a_w3, a_b3,
                                        c_w1, c_b1, c_w2, c_b2, c_w3, c_b3,
                                        (const unsigned int*)mask,
                                        (const unsigned int*)cand, F, scnt,
                                        psumP, pmaxP, cfw, aw1t, aw2t, cw1t, cw2t);
  pp_critic_kernel<<<128, 256, 0, stream>>>(psumP, pmaxP, aw1t, a_b1,
                                            cw1t, cw2t, c_b1, c_b2, c_w3, c_b3,
                                            F, pact, (void*)d_out);
  actorB_kernel<<<448, 256, 0, stream>>>(cfw, a_b2, a_w3, a_b3, mask, F, pact,
                                         aw1t, aw2t, scores, scnt, (void*)d_out);
}

// Round 16
// 157.431 us; speedup vs baseline: 1.0592x; 1.0206x over previous
//
#include <hip/hip_runtime.h>

#define NN 10000
#define NCAND 201
#define NB 64

typedef __attribute__((ext_vector_type(8))) short short8;
typedef __attribute__((ext_vector_type(4))) float f32x4;

__device__ __forceinline__ float bf2f(unsigned short u) {
  return __uint_as_float(((unsigned int)u) << 16);
}
__device__ __forceinline__ unsigned short f2bf(float f) {
  unsigned int u = __float_as_uint(f);
  u += 0x7FFFu + ((u >> 16) & 1u);   // RNE
  return (unsigned short)(u >> 16);
}
__device__ __forceinline__ float fast_tanh(float x) {
  return 1.0f - 2.0f / (__expf(2.0f * x) + 1.0f);
}
// generic load: flag=1 -> float32 array, flag=0 -> bf16 array
__device__ __forceinline__ float gld(const void* p, long i, int f) {
  return f ? ((const float*)p)[i] : bf2f(((const unsigned short*)p)[i]);
}

// ---------------------------------------------------------------------------
// MEGA launch (everything with no intra-launch dependencies):
//  [0,1024)    : feat_pool role -- atomic-free partial pooling into
//                psumP/pmaxP[(b*16+s)*128+col]. 78/79 chunks are full
//                (cnt==128): uniform fast path drops the per-element
//                row<cnt / m<cnt predication (R15: VALUBusy 57% with a
//                ~5us arithmetic floor -- guards were pure overhead).
//  [1024,1472) : actorA role -- candidate h1 -> layer2 features cf -> cfw.
//  [1472,1856) : transpose aw1t/aw2t/cw1t/cw2t (256-sample self-detect).
//  [1856,1873) : F[j] per-array f32 flags.  1873: mask mode.  1874: cand
//                width + zero scnt.
// R14 lesson: do NOT fold pp/critic into actorB (VGPR 196 cliff, -5 us).
// ---------------------------------------------------------------------------
__global__ __launch_bounds__(256, 4)
void mega_kernel(const void* __restrict__ x, const int* __restrict__ cand,
                 const void* w1, const void* b1, const void* w2, const void* b2,
                 const void* aw1, const void* ab1, const void* aw2, const void* ab2,
                 const void* aw3, const void* ab3,
                 const void* cw1, const void* cb1, const void* cw2, const void* cb2,
                 const void* cw3, const void* cb3,
                 const unsigned int* mask_w, const unsigned int* cand_w,
                 int* F, int* scnt,
                 float* __restrict__ psumP, float* __restrict__ pmaxP,
                 unsigned short* __restrict__ cfw,
                 unsigned short* __restrict__ aw1t, unsigned short* __restrict__ aw2t,
                 unsigned short* __restrict__ cw1t, unsigned short* __restrict__ cw2t) {
  __shared__ __align__(16) unsigned short pool[128 * 72];  // 18432 B overlay
  __shared__ float w1f[3 * 64];
  __shared__ float b1f[64];
  __shared__ float b2f[128];
  __shared__ int cnts[8];

  const int t = threadIdx.x;
  const int j = blockIdx.x;
  const int lane = t & 63;
  const int wv = t >> 6;

  if (j < 1472) {
    // ---- shared self-detect for fp/actorA roles: x,w1,b1,b2,w2,cand ----
    if (t < 8) cnts[t] = 0;
    __syncthreads();
    {
      if ((((const unsigned short*)x)[t] & 0x7F80u) >= 0x4300u) atomicAdd(&cnts[0], 1);
      if (t < 192 && (((const unsigned short*)w1)[t] & 0x7F80u) >= 0x4300u) atomicAdd(&cnts[1], 1);
      if (t < 64 && (((const unsigned short*)b1)[t] & 0x7F80u) >= 0x4300u) atomicAdd(&cnts[2], 1);
      if (t < 128 && (((const unsigned short*)b2)[t] & 0x7F80u) >= 0x4300u) atomicAdd(&cnts[3], 1);
      if ((((const unsigned short*)w2)[t] & 0x7F80u) >= 0x4300u) atomicAdd(&cnts[4], 1);
      int co = 0;
#pragma unroll
      for (int q = 0; q < 4; ++q) {
        int i = t * 4 + q;
        if ((i & 1) && cand_w[i] != 0u) co = 1;
      }
      if (co) atomicAdd(&cnts[5], 1);
    }
    __syncthreads();
    const int F0 = cnts[0] > 32, F1 = cnts[1] > 24, F2 = cnts[2] > 8;
    const int F4 = cnts[3] > 16, Fw2 = cnts[4] > 32, C64 = cnts[5] == 0;

    if (j < 1024) {
      // ================= feat_pool role =================
      unsigned short* h1s = pool;  // [128][72]
      const int b = j >> 4;
      const int s = j & 15;

      if (t < 192) w1f[t] = gld(w1, t, F1);
      if (t < 64) b1f[t] = gld(b1, t, F2);
      if (t < 128) b2f[t] = gld(b2, t, F4);

      // B fragments gathered from fe_w2 [k][n] (strided scalar, once/block)
      short8 bfr[2][2];
#pragma unroll
      for (int nl = 0; nl < 2; ++nl)
#pragma unroll
        for (int ks = 0; ks < 2; ++ks) {
          int col = wv * 32 + nl * 16 + (lane & 15);
          short8 v;
#pragma unroll
          for (int jj = 0; jj < 8; ++jj) {
            int k = (lane >> 4) * 8 + ks * 32 + jj;
            v[jj] = (short)f2bf(gld(w2, (long)k * 128 + col, Fw2));
          }
          bfr[nl][ks] = v;
        }
      __syncthreads();

      float csum[2] = {0.f, 0.f};
      float cmax[2] = {0.f, 0.f};
      const int m = t & 127;
      const int kg = t >> 7;

      float x0 = 0.f, x1 = 0.f, x2 = 0.f;
      if (s < 79) {
        int nb = s * 128;
        if (m < min(128, NN - nb)) {
          long xo = ((long)b * NN + nb + m) * 3;
          x0 = gld(x, xo, F0); x1 = gld(x, xo + 1, F0); x2 = gld(x, xo + 2, F0);
        }
      }

      for (int c = s; c < 79; c += 16) {
        int nb = c * 128;
        int cnt = (nb + 128 <= NN) ? 128 : (NN - nb);
        const bool full = (cnt == 128);  // uniform across block
        if (full) {
#pragma unroll
          for (int blk = 0; blk < 4; ++blk) {
            short8 v;
#pragma unroll
            for (int i = 0; i < 8; ++i) {
              int k = kg * 32 + blk * 8 + i;
              float vv = x0 * w1f[k] + x1 * w1f[64 + k] + x2 * w1f[128 + k] + b1f[k];
              v[i] = (short)f2bf(fmaxf(vv, 0.f));
            }
            *(short8*)(h1s + m * 72 + kg * 32 + blk * 8) = v;
          }
        } else if (m < cnt) {
#pragma unroll
          for (int blk = 0; blk < 4; ++blk) {
            short8 v;
#pragma unroll
            for (int i = 0; i < 8; ++i) {
              int k = kg * 32 + blk * 8 + i;
              float vv = x0 * w1f[k] + x1 * w1f[64 + k] + x2 * w1f[128 + k] + b1f[k];
              v[i] = (short)f2bf(fmaxf(vv, 0.f));
            }
            *(short8*)(h1s + m * 72 + kg * 32 + blk * 8) = v;
          }
        }
        {
          int cn = c + 16;
          float nx0 = 0.f, nx1 = 0.f, nx2 = 0.f;
          if (cn < 79) {
            int nbn = cn * 128;
            if (m < min(128, NN - nbn)) {
              long xo = ((long)b * NN + nbn + m) * 3;
              nx0 = gld(x, xo, F0); nx1 = gld(x, xo + 1, F0); nx2 = gld(x, xo + 2, F0);
            }
          }
          __syncthreads();
          x0 = nx0; x1 = nx1; x2 = nx2;
        }
        if (full) {
          // unchecked epilogue (all rows valid)
#pragma unroll
          for (int mt = 0; mt < 8; ++mt) {
            const unsigned short* ap = h1s + (mt * 16 + (lane & 15)) * 72 + ((lane >> 4) * 8);
            short8 af0 = *(const short8*)(ap);
            short8 af1 = *(const short8*)(ap + 32);
#pragma unroll
            for (int nl = 0; nl < 2; ++nl) {
              f32x4 acc = {0.f, 0.f, 0.f, 0.f};
              acc = __builtin_amdgcn_mfma_f32_16x16x32_bf16(af0, bfr[nl][0], acc, 0, 0, 0);
              acc = __builtin_amdgcn_mfma_f32_16x16x32_bf16(af1, bfr[nl][1], acc, 0, 0, 0);
              int col = wv * 32 + nl * 16 + (lane & 15);
              float bb = b2f[col];
#pragma unroll
              for (int r = 0; r < 4; ++r) {
                float v = fmaxf(acc[r] + bb, 0.f);
                csum[nl] += v;
                cmax[nl] = fmaxf(cmax[nl], v);
              }
            }
          }
        } else {
#pragma unroll
          for (int mt = 0; mt < 8; ++mt) {
            const unsigned short* ap = h1s + (mt * 16 + (lane & 15)) * 72 + ((lane >> 4) * 8);
            short8 af0 = *(const short8*)(ap);
            short8 af1 = *(const short8*)(ap + 32);
#pragma unroll
            for (int nl = 0; nl < 2; ++nl) {
              f32x4 acc = {0.f, 0.f, 0.f, 0.f};
              acc = __builtin_amdgcn_mfma_f32_16x16x32_bf16(af0, bfr[nl][0], acc, 0, 0, 0);
              acc = __builtin_amdgcn_mfma_f32_16x16x32_bf16(af1, bfr[nl][1], acc, 0, 0, 0);
              int col = wv * 32 + nl * 16 + (lane & 15);
              float bb = b2f[col];
#pragma unroll
              for (int r = 0; r < 4; ++r) {
                int row = mt * 16 + ((lane >> 4) * 4) + r;
                if (row < cnt) {
                  float v = fmaxf(acc[r] + bb, 0.f);
                  csum[nl] += v;
                  cmax[nl] = fmaxf(cmax[nl], v);
                }
              }
            }
          }
        }
        __syncthreads();
      }
#pragma unroll
      for (int nl = 0; nl < 2; ++nl) {
        csum[nl] += __shfl_xor(csum[nl], 16);
        csum[nl] += __shfl_xor(csum[nl], 32);
        cmax[nl] = fmaxf(cmax[nl], __shfl_xor(cmax[nl], 16));
        cmax[nl] = fmaxf(cmax[nl], __shfl_xor(cmax[nl], 32));
      }
      if (lane < 16) {
#pragma unroll
        for (int nl = 0; nl < 2; ++nl) {
          int col = wv * 32 + nl * 16 + lane;
          psumP[((long)b * 16 + s) * 128 + col] = csum[nl];   // plain stores
          pmaxP[((long)b * 16 + s) * 128 + col] = cmax[nl];
        }
      }
    } else {
      // ================= actorA role: h1c -> cf -> cfw =================
      unsigned short* h1c = pool;           // [32][72]
      const int idx = j - 1024;
      const int b = idx / 7;
      const int cb = idx % 7;
      const int cbase = cb * 29;

      if (t < 128) b2f[t] = gld(b2, t, F4);

      {
        int r = t & 31;
        int ci = cbase + r;
        if (ci > NCAND - 1) ci = NCAND - 1;
        long cidx = (long)b * NCAND + ci;
        int nd = C64 ? cand[2 * cidx] : cand[cidx];
        long xo = ((long)b * NN + nd) * 3;
        float x0 = gld(x, xo, F0), x1 = gld(x, xo + 1, F0), x2 = gld(x, xo + 2, F0);
        int kg = t >> 5;
#pragma unroll
        for (int i = 0; i < 8; ++i) {
          int k = kg * 8 + i;
          float v = x0 * gld(w1, k, F1) + x1 * gld(w1, 64 + k, F1) +
                    x2 * gld(w1, 128 + k, F1) + gld(b1, k, F2);
          h1c[r * 72 + k] = f2bf(fmaxf(v, 0.f));
        }
      }
      __syncthreads();

      {
        short8 af[2][2];
#pragma unroll
        for (int mt = 0; mt < 2; ++mt)
#pragma unroll
          for (int ks = 0; ks < 2; ++ks)
            af[mt][ks] = *(const short8*)(h1c + (mt * 16 + (lane & 15)) * 72 + ((lane >> 4) * 8) + ks * 32);
#pragma unroll
        for (int nl = 0; nl < 2; ++nl) {
          int col = wv * 32 + nl * 16 + (lane & 15);
          short8 bf0, bf1;
#pragma unroll
          for (int jj = 0; jj < 8; ++jj) {
            int k = (lane >> 4) * 8 + jj;
            bf0[jj] = (short)f2bf(gld(w2, (long)k * 128 + col, Fw2));
            bf1[jj] = (short)f2bf(gld(w2, (long)(k + 32) * 128 + col, Fw2));
          }
          float bb = b2f[col];
#pragma unroll
          for (int mt = 0; mt < 2; ++mt) {
            f32x4 acc = {0.f, 0.f, 0.f, 0.f};
            acc = __builtin_amdgcn_mfma_f32_16x16x32_bf16(af[mt][0], bf0, acc, 0, 0, 0);
            acc = __builtin_amdgcn_mfma_f32_16x16x32_bf16(af[mt][1], bf1, acc, 0, 0, 0);
#pragma unroll
            for (int r = 0; r < 4; ++r) {
              int row = mt * 16 + ((lane >> 4) * 4) + r;
              cfw[(long)idx * 4096 + row * 128 + col] = f2bf(fmaxf(acc[r] + bb, 0.f));
            }
          }
        }
      }
    }
    return;
  }

  // ---- housekeeping roles ----
  if (t < 8) cnts[t] = 0;
  __syncthreads();

  if (j < 1856) {
    const unsigned short* pa = (const unsigned short*)aw1;
    const unsigned short* pb = (const unsigned short*)aw2;
    const unsigned short* pc = (const unsigned short*)cw1;
    const unsigned short* pd = (const unsigned short*)cw2;
    if ((pa[t] & 0x7F80u) >= 0x4300u) atomicAdd(&cnts[0], 1);
    if ((pb[t] & 0x7F80u) >= 0x4300u) atomicAdd(&cnts[1], 1);
    if ((pc[t] & 0x7F80u) >= 0x4300u) atomicAdd(&cnts[2], 1);
    if ((pd[t] & 0x7F80u) >= 0x4300u) atomicAdd(&cnts[3], 1);
    __syncthreads();
    const int Faw1 = cnts[0] > 32, Faw2 = cnts[1] > 32;
    const int Fcw1 = cnts[2] > 32, Fcw2 = cnts[3] > 32;
    int i = (j - 1472) * 256 + t;
    if (i < 256 * 384) { int n = i / 384, k = i % 384; aw1t[i] = f2bf(gld(aw1, k * 256 + n, Faw1)); }
    if (i < 256 * 256) {
      int n = i >> 8, k = i & 255;
      aw2t[i] = f2bf(gld(aw2, k * 256 + n, Faw2));
      cw1t[i] = f2bf(gld(cw1, k * 256 + n, Fcw1));
      cw2t[i] = f2bf(gld(cw2, k * 256 + n, Fcw2));
    }
  } else if (j < 1873) {
    const void* ptrs[17] = {x, w1, b1, w2, b2, aw1, ab1, aw2, ab2, aw3, ab3,
                            cw1, cb1, cw2, cb2, cw3, cb3};
    const int sizes[17] = {1920000, 192, 64, 8192, 128, 98304, 256, 65536, 256,
                           256, 1, 65536, 256, 65536, 256, 256, 1};
    int a = j - 1856;
    const unsigned short* p = (const unsigned short*)ptrs[a];
    int K = min(sizes[a], 2048);
    int c = 0;
    for (int i = t; i < K; i += 256)
      if ((p[i] & 0x7F80u) >= 0x4300u) c++;
    if (c) atomicAdd(&cnts[0], c);
    __syncthreads();
    if (t == 0) F[a] = (cnts[0] > (K >> 3)) ? 1 : 0;
  } else if (j == 1873) {
    int flo = 0, fhi = 0, fgt = 0;
    for (int i = t; i < 3216; i += 256) {
      unsigned int w = mask_w[i];
      if ((w & 0xFFFFu) == 0x3F80u) flo = 1;
      if ((w >> 16) == 0x3F80u) fhi = 1;
      if (w > 1u) fgt = 1;
    }
    if (flo) cnts[0] = 1;
    if (fhi) cnts[1] = 1;
    if (fgt) cnts[2] = 1;
    __syncthreads();
    if (t == 0) F[17] = cnts[0] ? 2 : (cnts[1] ? 3 : (cnts[2] ? 1 : 0));
  } else {
    int co = 0;
    for (int i = t; i < 1024; i += 256)
      if ((i & 1) && cand_w[i] != 0u) co = 1;
    if (co) cnts[0] = 1;
    if (t < 64) scnt[t] = 0;
    __syncthreads();
    if (t == 0) F[18] = cnts[0] ? 0 : 1;
  }
}

// ---------------------------------------------------------------------------
// blocks 0..63: pooled projection -> pact; blocks 64..127: critic -> v
// both reduce the 16 per-slice pooling partials (deterministic order)
// ---------------------------------------------------------------------------
__global__ __launch_bounds__(256)
void pp_critic_kernel(const float* __restrict__ psumP, const float* __restrict__ pmaxP,
                      const unsigned short* __restrict__ aw1t,
                      const void* __restrict__ ab1,
                      const unsigned short* __restrict__ cw1t,
                      const unsigned short* __restrict__ cw2t,
                      const void* __restrict__ cb1, const void* __restrict__ cb2,
                      const void* __restrict__ cw3, const void* __restrict__ cb3,
                      const int* __restrict__ F,
                      float* __restrict__ pact, void* __restrict__ out) {
  __shared__ float plf[256];
  __shared__ float c1f[256];
  __shared__ float red[4];
  const int t = threadIdx.x;
  const int b = blockIdx.x & 63;
  const int lane = t & 63, wv = t >> 6;

  float ssum = 0.f, smax = 0.f;
  if (t < 128) {
#pragma unroll
    for (int sl = 0; sl < 16; ++sl) {
      ssum += psumP[((long)b * 16 + sl) * 128 + t];
      smax = fmaxf(smax, pmaxP[((long)b * 16 + sl) * 128 + t]);
    }
  }

  if (blockIdx.x < 64) {
    const int F6 = F[6];
    if (t < 128) {
      plf[t] = bf2f(f2bf(ssum * (1.0f / 10000.0f)));  // match actor bf16 quant
      plf[128 + t] = bf2f(f2bf(smax));
    }
    __syncthreads();
    float a = gld(ab1, t, F6);
    const unsigned short* row = aw1t + t * 384 + 128;
#pragma unroll
    for (int k8 = 0; k8 < 32; ++k8) {
      short8 w = *(const short8*)(row + k8 * 8);
#pragma unroll
      for (int j = 0; j < 8; ++j)
        a += plf[k8 * 8 + j] * bf2f((unsigned short)w[j]);
    }
    pact[b * 256 + t] = a;
  } else {
    const int OF = (F[0] + F[1] + F[3] + F[5] + F[7] + F[9] + F[11] + F[13] + F[15]) >= 5;
    const int F12 = F[12], F14 = F[14], F15 = F[15], F16 = F[16];
    if (t < 128) {
      plf[t] = ssum * (1.0f / 10000.0f);
      plf[128 + t] = smax;
    }
    __syncthreads();
    {
      float a = gld(cb1, t, F12);
      const unsigned short* row = cw1t + t * 256;
#pragma unroll
      for (int k8 = 0; k8 < 32; ++k8) {
        short8 w = *(const short8*)(row + k8 * 8);
#pragma unroll
        for (int j = 0; j < 8; ++j)
          a += plf[k8 * 8 + j] * bf2f((unsigned short)w[j]);
      }
      c1f[t] = fast_tanh(a);
    }
    __syncthreads();
    {
      float a2 = gld(cb2, t, F14);
      const unsigned short* row = cw2t + t * 256;
#pragma unroll
      for (int k8 = 0; k8 < 32; ++k8) {
        short8 w = *(const short8*)(row + k8 * 8);
#pragma unroll
        for (int j = 0; j < 8; ++j)
          a2 += c1f[k8 * 8 + j] * bf2f((unsigned short)w[j]);
      }
      a2 = fast_tanh(a2);
      float p = a2 * gld(cw3, t, F15);
      for (int o = 32; o; o >>= 1) p += __shfl_xor(p, o);
      __syncthreads();
      if (lane == 0) red[wv] = p;
      __syncthreads();
      if (t == 0) {
        float v = red[0] + red[1] + red[2] + red[3] + gld(cb3, 0, F16);
        if (!(v == v)) v = 0.f;  // scrub
        if (OF) ((float*)out)[NB * NCAND + b] = v;
        else ((unsigned short*)out)[NB * NCAND + b] = f2bf(v);
      }
    }
  }
}

// ---------------------------------------------------------------------------
// actorB: layers 1-3 from cfw + pact -> scores; the LAST cand-block of each
// batch (per-batch counter) runs the masked softmax. scores via device-scope
// atomicExch; tail reads via atomicAdd(p,0) -- coherent across XCDs (G16).
// ---------------------------------------------------------------------------
__global__ __launch_bounds__(256)
void actorB_kernel(const unsigned short* __restrict__ cfw,
                   const void* __restrict__ ab2,
                   const void* __restrict__ aw3, const void* __restrict__ ab3,
                   const void* __restrict__ mask,
                   const int* __restrict__ F,
                   const float* __restrict__ pact,
                   const unsigned short* __restrict__ aw1t,
                   const unsigned short* __restrict__ aw2t,
                   float* __restrict__ scores, int* __restrict__ scnt,
                   void* __restrict__ out) {
  __shared__ __align__(16) unsigned short a1s[32 * 264];
  __shared__ __align__(16) unsigned short a2s[32 * 264];
  __shared__ float pactS[256], ab2f[256];
  __shared__ float red[4];
  __shared__ int amLast;

  const int t = threadIdx.x;
  const int b = blockIdx.x / 7;
  const int cb = blockIdx.x % 7;
  const int cbase = cb * 29;
  const int cntc = min(29, NCAND - cbase);
  const int lane = t & 63;
  const int wv = t >> 6;
  const int F8 = F[8], F9 = F[9], F10 = F[10];

  pactS[t] = pact[b * 256 + t];
  ab2f[t] = gld(ab2, t, F8);

  // actor layer 1 (candidate part): [32 x 128] @ [128 x 256] + pact
  {
    f32x4 acc[2][4];
#pragma unroll
    for (int mt = 0; mt < 2; ++mt)
#pragma unroll
      for (int nt = 0; nt < 4; ++nt) acc[mt][nt] = (f32x4){0.f, 0.f, 0.f, 0.f};
    const unsigned short* cfb = cfw + (long)blockIdx.x * 4096;
#pragma unroll
    for (int ks = 0; ks < 4; ++ks) {
      short8 af0 = *(const short8*)(cfb + (lane & 15) * 128 + ks * 32 + ((lane >> 4) * 8));
      short8 af1 = *(const short8*)(cfb + (16 + (lane & 15)) * 128 + ks * 32 + ((lane >> 4) * 8));
#pragma unroll
      for (int nt = 0; nt < 4; ++nt) {
        int col = wv * 64 + nt * 16 + (lane & 15);
        short8 bfr = *(const short8*)(aw1t + col * 384 + ks * 32 + ((lane >> 4) * 8));
        acc[0][nt] = __builtin_amdgcn_mfma_f32_16x16x32_bf16(af0, bfr, acc[0][nt], 0, 0, 0);
        acc[1][nt] = __builtin_amdgcn_mfma_f32_16x16x32_bf16(af1, bfr, acc[1][nt], 0, 0, 0);
      }
    }
    __syncthreads();
#pragma unroll
    for (int mt = 0; mt < 2; ++mt)
#pragma unroll
      for (int nt = 0; nt < 4; ++nt) {
        int col = wv * 64 + nt * 16 + (lane & 15);
        float bb = pactS[col];
#pragma unroll
        for (int r = 0; r < 4; ++r) {
          int row = mt * 16 + ((lane >> 4) * 4) + r;
          a1s[row * 264 + col] = f2bf(fast_tanh(acc[mt][nt][r] + bb));
        }
      }
  }
  __syncthreads();

  // actor layer 2: [32 x 256] @ [256 x 256]
  {
    f32x4 acc[2][4];
#pragma unroll
    for (int mt = 0; mt < 2; ++mt)
#pragma unroll
      for (int nt = 0; nt < 4; ++nt) acc[mt][nt] = (f32x4){0.f, 0.f, 0.f, 0.f};
    for (int ks = 0; ks < 8; ++ks) {
      short8 af0 = *(const short8*)(a1s + (lane & 15) * 264 + ks * 32 + ((lane >> 4) * 8));
      short8 af1 = *(const short8*)(a1s + (16 + (lane & 15)) * 264 + ks * 32 + ((lane >> 4) * 8));
#pragma unroll
      for (int nt = 0; nt < 4; ++nt) {
        int col = wv * 64 + nt * 16 + (lane & 15);
        short8 bfr = *(const short8*)(aw2t + col * 256 + ks * 32 + ((lane >> 4) * 8));
        acc[0][nt] = __builtin_amdgcn_mfma_f32_16x16x32_bf16(af0, bfr, acc[0][nt], 0, 0, 0);
        acc[1][nt] = __builtin_amdgcn_mfma_f32_16x16x32_bf16(af1, bfr, acc[1][nt], 0, 0, 0);
      }
    }
#pragma unroll
    for (int mt = 0; mt < 2; ++mt)
#pragma unroll
      for (int nt = 0; nt < 4; ++nt) {
        int col = wv * 64 + nt * 16 + (lane & 15);
        float bb = ab2f[col];
#pragma unroll
        for (int r = 0; r < 4; ++r) {
          int row = mt * 16 + ((lane >> 4) * 4) + r;
          a2s[row * 264 + col] = f2bf(fast_tanh(acc[mt][nt][r] + bb));
        }
      }
  }
  __syncthreads();

  // layer 3: per-row dot-256 with a_w3 -> scores (device-scope atomicExch)
  {
    int row = t >> 3, seg = t & 7;
    float p = 0.f;
#pragma unroll 8
    for (int i = 0; i < 32; ++i) {
      int k = seg * 32 + i;
      p += bf2f(a2s[row * 264 + k]) * gld(aw3, k, F9);
    }
    p += __shfl_xor(p, 1);
    p += __shfl_xor(p, 2);
    p += __shfl_xor(p, 4);
    if (seg == 0 && row < cntc)
      atomicExch(&scores[b * 256 + cbase + row], p + gld(ab3, 0, F10));
  }
  __syncthreads();

  if (t == 0) {
    __threadfence();
    amLast = (atomicAdd(&scnt[b], 1) == 6);
  }
  __syncthreads();
  if (!amLast) return;

  // ---- masked softmax tail (last cand-block of this batch) ----
  const int MM = F[17];
  const int OF = (F[0] + F[1] + F[3] + F[5] + F[7] + F[9] + F[11] + F[13] + F[15]) >= 5;
  float sraw = 0.f, sv = -1e30f;
  bool valid = false;
  if (t < NCAND) {
    sraw = atomicAdd(&scores[b * 256 + t], 0.0f);   // coherent read
    long idx = (long)b * NCAND + t;
    if (MM == 0)      valid = ((const int*)mask)[idx] != 0;
    else if (MM == 1) valid = ((const unsigned char*)mask)[idx] != 0;
    else if (MM == 2) valid = ((const unsigned short*)mask)[idx] != 0;
    else              valid = ((const unsigned int*)mask)[idx] != 0;
    if (valid) sv = sraw;
  }
  float m = sv;
  for (int o = 32; o; o >>= 1) m = fmaxf(m, __shfl_xor(m, o));
  if (lane == 0) red[wv] = m;
  __syncthreads();
  m = fmaxf(fmaxf(red[0], red[1]), fmaxf(red[2], red[3]));
  __syncthreads();
  float e = valid ? __expf(sraw - m) : 0.f;
  if (!(e == e)) e = 0.f;  // scrub
  float ss = e;
  for (int o = 32; o; o >>= 1) ss += __shfl_xor(ss, o);
  if (lane == 0) red[wv] = ss;
  __syncthreads();
  float tot = red[0] + red[1] + red[2] + red[3];
  tot = fmaxf(tot, 1e-30f);
  if (t < NCAND) {
    float pv = e / tot;
    if (!(pv == pv)) pv = 0.f;  // scrub
    if (OF) ((float*)out)[b * NCAND + t] = pv;
    else ((unsigned short*)out)[b * NCAND + t] = f2bf(pv);
  }
}

// ---------------------------------------------------------------------------
extern "C" void kernel_launch(void* const* d_in, const int* in_sizes, int n_in,
                              void* d_out, int out_size, void* d_ws, size_t ws_size,
                              hipStream_t stream) {
  const void* x = d_in[0];
  const int* cand = (const int*)d_in[1];
  const void* mask = d_in[2];
  const void* fe_w1 = d_in[3];
  const void* fe_b1 = d_in[4];
  const void* fe_w2 = d_in[5];
  const void* fe_b2 = d_in[6];
  const void* a_w1 = d_in[7];
  const void* a_b1 = d_in[8];
  const void* a_w2 = d_in[9];
  const void* a_b2 = d_in[10];
  const void* a_w3 = d_in[11];
  const void* a_b3 = d_in[12];
  const void* c_w1 = d_in[13];
  const void* c_b1 = d_in[14];
  const void* c_w2 = d_in[15];
  const void* c_b2 = d_in[16];
  const void* c_w3 = d_in[17];
  const void* c_b3 = d_in[18];

  char* ws = (char*)d_ws;
  float* scores = (float*)(ws + 65536);                   // 64*256 f32
  unsigned short* aw1t = (unsigned short*)(ws + 147456);  // 256*384 bf16
  unsigned short* aw2t = (unsigned short*)(ws + 344064);  // 256*256 bf16
  int* F = (int*)(ws + 475136);                           // 20 ints
  unsigned short* cw1t = (unsigned short*)(ws + 475264);  // 256*256 bf16
  unsigned short* cw2t = (unsigned short*)(ws + 606336);  // 256*256 bf16
  float* pact = (float*)(ws + 737408);                    // 64*256 f32
  unsigned short* cfw = (unsigned short*)(ws + 802944);   // 448*4096 bf16
  int* scnt = (int*)(ws + 4472960);                       // 64 ints
  float* psumP = (float*)(ws + 4473216);                  // 64*16*128 f32
  float* pmaxP = (float*)(ws + 4997504);                  // 64*16*128 f32 (ends 5521792)

  mega_kernel<<<1875, 256, 0, stream>>>(x, cand, fe_w1, fe_b1, fe_w2, fe_b2,
                                        a_w1, a_b1, a_w2, a_b2, a_w3, a_b3,
                                        c_w1, c_b1, c_w2, c_b2, c_w3, c_b3,
                                        (const unsigned int*)mask,
                                        (const unsigned int*)cand, F, scnt,
                                        psumP, pmaxP, cfw, aw1t, aw2t, cw1t, cw2t);
  pp_critic_kernel<<<128, 256, 0, stream>>>(psumP, pmaxP, aw1t, a_b1,
                                            cw1t, cw2t, c_b1, c_b2, c_w3, c_b3,
                                            F, pact, (void*)d_out);
  actorB_kernel<<<448, 256, 0, stream>>>(cfw, a_b2, a_w3, a_b3, mask, F, pact,
                                         aw1t, aw2t, scores, scnt, (void*)d_out);
}